// Round 20
// baseline (5790.133 us; speedup 1.0000x reference)
//
#include <hip/hip_runtime.h>

// CharRNN: 3-layer shared-weight LSTM (H=65) over T=4096, B=50, + dense head.
//
// Round-20: R19 + RACE FIX. R19's post-timing divergence exposed a latent
// race present since R9: the zero-init loop (tids 0..203 write s_hin[0][*]=0)
// and the prefetch threads' initial s_hin[0][pidx]=x(0) write were not
// separated by a barrier — the benign order only won because the prefetch
// write sits behind a global load. Fix: __syncthreads() between them (one
// barrier per launch, zero cost). Everything else identical to R19, keeping
// the wpe(2,3) A/B: does min=2 restore the 88-VGPR grant at 768 threads
// (R18 got 76 at wpe(3,3) -> ~12-float remat tax on gate threads)?

#define HH    65
#define G4    260
#define TT    4096
#define NB    50
#define BLOCK 768
#define NGATE 512
#define DROWS 64

#define KEEP4(v) asm volatile("" : "+v"(v.x), "+v"(v.y), "+v"(v.z), "+v"(v.w))
#define KEEP(s)  asm volatile("" : "+v"(s))

__device__ __forceinline__ float sigm(float x)  { return 1.0f / (1.0f + __expf(-x)); }
__device__ __forceinline__ float tanha(float x) { float e = __expf(2.0f * x); return 1.0f - 2.0f / (e + 1.0f); }

// sum across the 4 lanes of a quad (lane bits 0-1) via DPP; all 4 lanes get total
__device__ __forceinline__ float qsum(float v) {
    int i = __float_as_int(v);
    v += __int_as_float(__builtin_amdgcn_update_dpp(0, i, 0xB1, 0xF, 0xF, true)); // [1,0,3,2]
    i = __float_as_int(v);
    v += __int_as_float(__builtin_amdgcn_update_dpp(0, i, 0x4E, 0xF, 0xF, true)); // [2,3,0,1]
    return v;
}

__global__ void __launch_bounds__(BLOCK)
__attribute__((amdgpu_waves_per_eu(2, 3)))
charrnn_rec(const float* __restrict__ x, const float* __restrict__ W,
            const float* __restrict__ U, const float* __restrict__ bv,
            float* __restrict__ out)
{
    __shared__ __align__(16) float s_hin[3][68];    // input to layer l (row0 = x(t)); [65..67]=0
    __shared__ __align__(16) float s_hrec[3][68];   // recurrent h per layer
    __shared__ __align__(16) float s_z[3][2][256];  // [layer][side][col] dots, cols 0..255
    __shared__ float s_parte[3][2][4];              // [layer][side][col-256] dots, cols 256..259

    const int bat = blockIdx.x;
    const int tid = threadIdx.x;
    const float* xb   = x   + (size_t)bat * TT * HH;
    float*       outb = out + (size_t)bat * TT * HH;

    for (int i = tid; i < 3 * 68; i += BLOCK) { (&s_hin[0][0])[i] = 0.0f; (&s_hrec[0][0])[i] = 0.0f; }

    const bool isG  = (tid < NGATE);
    const int  atid = tid - NGATE;        // aux id 0..255 (aux threads)
    const int  awv  = (atid >> 6) & 3;    // aux wave 0..3 (block waves 8..11 -> SIMD 0..3)
    const int  al   = atid & 63;          // aux lane

    // ---------------- gate role (tid < 512): EXACT R9 main-dot ----------------
    const int w    = tid & 3;             // k-window: rows 16w..16w+15 (+ row 64 on w==3)
    const int side = tid >> 8;            // 0 = W (reads hin), 1 = U (reads hrec)
    const int col0 = ((tid >> 2) & 63) * 4;
    const float* M = side ? U : W;

    float4 wa0, wa1, wa2, wa3, wb0, wb1, wb2, wb3,
           wc0, wc1, wc2, wc3, wd0, wd1, wd2, wd3;
#define WLD(v, c, q)                                                          \
    do {                                                                      \
        v.x = isG ? M[(16 * w + 4 * (q) + 0) * G4 + col0 + (c)] : 0.0f;       \
        v.y = isG ? M[(16 * w + 4 * (q) + 1) * G4 + col0 + (c)] : 0.0f;       \
        v.z = isG ? M[(16 * w + 4 * (q) + 2) * G4 + col0 + (c)] : 0.0f;       \
        v.w = isG ? M[(16 * w + 4 * (q) + 3) * G4 + col0 + (c)] : 0.0f;       \
        KEEP4(v);                                                             \
    } while (0)
    WLD(wa0, 0, 0); WLD(wa1, 0, 1); WLD(wa2, 0, 2); WLD(wa3, 0, 3);
    WLD(wb0, 1, 0); WLD(wb1, 1, 1); WLD(wb2, 1, 2); WLD(wb3, 1, 3);
    WLD(wc0, 2, 0); WLD(wc1, 2, 1); WLD(wc2, 2, 2); WLD(wc3, 2, 3);
    WLD(wd0, 3, 0); WLD(wd1, 3, 1); WLD(wd2, 3, 2); WLD(wd3, 3, 3);
#undef WLD
    float ws0 = (isG && w == 3) ? M[64 * G4 + col0 + 0] : 0.0f; KEEP(ws0);
    float ws1 = (isG && w == 3) ? M[64 * G4 + col0 + 1] : 0.0f; KEEP(ws1);
    float ws2 = (isG && w == 3) ? M[64 * G4 + col0 + 2] : 0.0f; KEEP(ws2);
    float ws3 = (isG && w == 3) ? M[64 * G4 + col0 + 3] : 0.0f; KEEP(ws3);

    // ---------------- aux roles (tid >= 512) ----------------
    // extras: lanes 0..7 of each aux wave; col 256+awv; es = lane>>2 (side), ew = lane&3
    const bool isE = (!isG) && (al < 8);
    const int  es  = (al >> 2) & 1;
    const int  ew  = al & 3;
    const int  colE = 256 + awv;
    const float* ME = es ? U : W;
    float4 e0, e1, e2, e3;
#define ELD(v, q)                                                             \
    do {                                                                      \
        v.x = isE ? ME[(16 * ew + 4 * (q) + 0) * G4 + colE] : 0.0f;           \
        v.y = isE ? ME[(16 * ew + 4 * (q) + 1) * G4 + colE] : 0.0f;           \
        v.z = isE ? ME[(16 * ew + 4 * (q) + 2) * G4 + colE] : 0.0f;           \
        v.w = isE ? ME[(16 * ew + 4 * (q) + 3) * G4 + colE] : 0.0f;           \
        KEEP4(v);                                                             \
    } while (0)
    ELD(e0, 0); ELD(e1, 1); ELD(e2, 2); ELD(e3, 3);
#undef ELD
    float esc = (isE && ew == 3) ? ME[64 * G4 + colE] : 0.0f; KEEP(esc);

    // Phase B: waves 8..10 -> layer awv, cell al (0..63); wave 11 lanes 0..2 -> layer al, cell 64
    const bool isB  = (!isG) && (awv < 3);
    const bool isB64 = (!isG) && (awv == 3) && (al < 3);
    const int  cl = isB ? awv : (isB64 ? al : 0);
    const int  cn = isB ? al : 64;
    const bool anyB = isB || isB64;
    const float bz0 = anyB ? bv[cn]       : 0.0f;
    const float bz1 = anyB ? bv[65 + cn]  : 0.0f;
    const float bz2 = anyB ? bv[130 + cn] : 0.0f;
    const float bz3 = anyB ? bv[195 + cn] : 0.0f;
    float creg = 0.0f;

    // prefetch: wave 11 lanes 0..63 -> pidx = al; lane 63 also handles pidx 64
    const bool isP  = (!isG) && (awv == 3);
    const bool isP2 = isP && (al == 63);
    const int  pidx = al;
    float cur0 = 0.0f, nxt0 = 0.0f, cur1 = 0.0f, nxt1 = 0.0f;

    __syncthreads();   // RACE FIX: zero-init must complete before x(0) lands in s_hin[0]

    if (isP) {
        s_hin[0][pidx] = xb[pidx];
        cur0 = xb[HH + pidx];
        if (isP2) { s_hin[0][64] = xb[64]; cur1 = xb[HH + 64]; }
    }
    __syncthreads();

    for (int r = 0; r < TT + 2; ++r) {
        // ---------------- Phase A ----------------
        if (isP) {  // issue x(r+2) early
            const int tn = r + 2;
            nxt0 = (tn < TT) ? xb[(size_t)tn * HH + pidx] : 0.0f;
            if (isP2) nxt1 = (tn < TT) ? xb[(size_t)tn * HH + 64] : 0.0f;
        }
        if (isG) {
#pragma unroll
            for (int l = 0; l < 3; ++l) {
                if ((unsigned)(r - l) < TT) {
                    const float* hb = side ? &s_hrec[l][0] : &s_hin[l][0];
                    const float4* h4 = (const float4*)(hb + 16 * w);
                    const float4 H0 = h4[0], H1 = h4[1], H2 = h4[2], H3 = h4[3];
                    const float  h64 = hb[64];
                    float a0, a1, a2, a3;
#define COLDOT(acc, p0, p1, p2, p3, ps)                                       \
    {   float u0, u1;                                                         \
        u0 = H0.x * p0.x;           u1 = H0.y * p0.y;                         \
        u0 = fmaf(H0.z, p0.z, u0);  u1 = fmaf(H0.w, p0.w, u1);                \
        u0 = fmaf(H1.x, p1.x, u0);  u1 = fmaf(H1.y, p1.y, u1);                \
        u0 = fmaf(H1.z, p1.z, u0);  u1 = fmaf(H1.w, p1.w, u1);                \
        u0 = fmaf(H2.x, p2.x, u0);  u1 = fmaf(H2.y, p2.y, u1);                \
        u0 = fmaf(H2.z, p2.z, u0);  u1 = fmaf(H2.w, p2.w, u1);                \
        u0 = fmaf(H3.x, p3.x, u0);  u1 = fmaf(H3.y, p3.y, u1);                \
        u0 = fmaf(H3.z, p3.z, u0);  u1 = fmaf(H3.w, p3.w, u1);                \
        u0 = fmaf(h64, ps, u0);                                               \
        acc = u0 + u1; }
                    COLDOT(a0, wa0, wa1, wa2, wa3, ws0)
                    COLDOT(a1, wb0, wb1, wb2, wb3, ws1)
                    COLDOT(a2, wc0, wc1, wc2, wc3, ws2)
                    COLDOT(a3, wd0, wd1, wd2, wd3, ws3)
                    a0 = qsum(a0); a1 = qsum(a1); a2 = qsum(a2); a3 = qsum(a3);
                    if (w == 0)
                        *(float4*)&s_z[l][side][col0] = make_float4(a0, a1, a2, a3);
                }
            }
        } else if (isE) {
#pragma unroll
            for (int l = 0; l < 3; ++l) {
                if ((unsigned)(r - l) < TT) {
                    const float* hb = es ? &s_hrec[l][0] : &s_hin[l][0];
                    const float4* h4 = (const float4*)(hb + 16 * ew);
                    const float4 H0 = h4[0], H1 = h4[1], H2 = h4[2], H3 = h4[3];
                    const float  h64 = hb[64];
                    float ea;
                    COLDOT(ea, e0, e1, e2, e3, esc)
                    ea = qsum(ea);                 // quad-reduce over ew (4 lanes, same es)
                    if (ew == 0) s_parte[l][es][awv] = ea;
                }
            }
#undef COLDOT
        }
        __syncthreads();

        // ---------------- Phase B (aux waves) ----------------
        if (anyB) {
            if ((unsigned)(r - cl) < TT) {
                const float zi = bz0 + s_z[cl][0][cn]       + s_z[cl][1][cn];
                const float zf = bz1 + s_z[cl][0][65 + cn]  + s_z[cl][1][65 + cn];
                const float zg = bz2 + s_z[cl][0][130 + cn] + s_z[cl][1][130 + cn];
                float zo;
                if (cn < 61) zo = bz3 + s_z[cl][0][195 + cn]    + s_z[cl][1][195 + cn];
                else         zo = bz3 + s_parte[cl][0][cn - 61] + s_parte[cl][1][cn - 61];
                const float ig = sigm(zi), fg = sigm(zf), gg = tanha(zg), og = sigm(zo);
                creg = fmaf(fg, creg, ig * gg);
                const float h = og * tanha(creg);
                s_hrec[cl][cn] = h;
                if (cl < 2) s_hin[cl + 1][cn] = h;
                else        outb[(size_t)(r - cl) * HH + cn] = h;   // stream h2 to out
            }
        }
        if (isP) {
            if (r + 1 < TT) {
                s_hin[0][pidx] = cur0;
                if (isP2) s_hin[0][64] = cur1;
            }
            cur0 = nxt0; cur1 = nxt1;
        }
        __syncthreads();
    }
}

// ---- kernel 2: in-place dense head over d_out: y = h2 @ Wd + bd ----
__global__ void __launch_bounds__(256, 1)
dense_head(float* __restrict__ io, const float* __restrict__ Wd, const float* __restrict__ bd)
{
    __shared__ __align__(16) float s_h[DROWS][68];
    __shared__ float s_wd[HH][HH];
    __shared__ float s_bd[HH];

    const int tid = threadIdx.x;
    float* base = io + (size_t)blockIdx.x * DROWS * HH;

    for (int i = tid; i < DROWS * HH; i += 256) {
        const int row = i / HH, k = i - row * HH;
        s_h[row][k] = base[i];
    }
    for (int i = tid; i < HH * HH; i += 256) (&s_wd[0][0])[i] = Wd[i];
    if (tid < HH) s_bd[tid] = bd[tid];
    __syncthreads();

    for (int u = tid; u < DROWS * HH; u += 256) {
        const int row = u / HH, c = u - row * HH;
        const float4* hp = (const float4*)&s_h[row][0];
        float acc = s_bd[c];
#pragma unroll
        for (int k4 = 0; k4 < 16; ++k4) {
            const float4 hv = hp[k4];
            acc = fmaf(hv.x, s_wd[4 * k4 + 0][c], acc);
            acc = fmaf(hv.y, s_wd[4 * k4 + 1][c], acc);
            acc = fmaf(hv.z, s_wd[4 * k4 + 2][c], acc);
            acc = fmaf(hv.w, s_wd[4 * k4 + 3][c], acc);
        }
        acc = fmaf(s_h[row][64], s_wd[64][c], acc);
        base[u] = acc;   // safe: all reads come from LDS copies
    }
}

extern "C" void kernel_launch(void* const* d_in, const int* in_sizes, int n_in,
                              void* d_out, int out_size, void* d_ws, size_t ws_size,
                              hipStream_t stream)
{
    const float* x  = (const float*)d_in[0];
    const float* W  = (const float*)d_in[1];
    const float* U  = (const float*)d_in[2];
    const float* bv = (const float*)d_in[3];
    const float* Wd = (const float*)d_in[4];
    const float* bd = (const float*)d_in[5];
    float* out = (float*)d_out;

    hipLaunchKernelGGL(charrnn_rec, dim3(NB), dim3(BLOCK), 0, stream, x, W, U, bv, out);
    hipLaunchKernelGGL(dense_head, dim3(NB * TT / DROWS), dim3(256), 0, stream, out, Wd, bd);
}

// Round 21
// 5588.882 us; speedup vs baseline: 1.0360x; 1.0360x over previous
//
#include <hip/hip_runtime.h>

// CharRNN: 3-layer shared-weight LSTM (H=65) over T=4096, B=50, + dense head.
//
// Round-21: R20 with the gate live-set shrunk to the 76-VGPR grant.
//   (a) Row-64 tail moved OUT of gate threads: gates compute rows 0..63 only
//       (exactly 64 weight floats; ws0-3 + h64 read/fmaf deleted). Tails
//       (hin64*W64[c] + hrec64*U64[c]) are added in Phase B by aux threads
//       (8 tail weights in registers); h64 values preloaded during Phase A
//       (stable there) to avoid racing the cell-64 update in Phase B.
//       Extras (cols 256..259) keep their own tail via esc -> zo tail only
//       added for n<61.
//   (b) Block-wise H consumption (load h4[q], consume, next) to cut staged-H
//       peak liveness 16 -> ~4.
//   R20 evidence: grant=76 vs live~90 -> ~600 cyc/round remat tax (measured
//   1930 issue vs ~1300 static). Target: live-set ~76-80 = grant.

#define HH    65
#define G4    260
#define TT    4096
#define NB    50
#define BLOCK 768
#define NGATE 512
#define DROWS 64

#define KEEP4(v) asm volatile("" : "+v"(v.x), "+v"(v.y), "+v"(v.z), "+v"(v.w))
#define KEEP(s)  asm volatile("" : "+v"(s))

__device__ __forceinline__ float sigm(float x)  { return 1.0f / (1.0f + __expf(-x)); }
__device__ __forceinline__ float tanha(float x) { float e = __expf(2.0f * x); return 1.0f - 2.0f / (e + 1.0f); }

// sum across the 4 lanes of a quad (lane bits 0-1) via DPP; all 4 lanes get total
__device__ __forceinline__ float qsum(float v) {
    int i = __float_as_int(v);
    v += __int_as_float(__builtin_amdgcn_update_dpp(0, i, 0xB1, 0xF, 0xF, true)); // [1,0,3,2]
    i = __float_as_int(v);
    v += __int_as_float(__builtin_amdgcn_update_dpp(0, i, 0x4E, 0xF, 0xF, true)); // [2,3,0,1]
    return v;
}

__global__ void __launch_bounds__(BLOCK)
__attribute__((amdgpu_waves_per_eu(2, 3)))
charrnn_rec(const float* __restrict__ x, const float* __restrict__ W,
            const float* __restrict__ U, const float* __restrict__ bv,
            float* __restrict__ out)
{
    __shared__ __align__(16) float s_hin[3][68];    // input to layer l (row0 = x(t)); [65..67]=0
    __shared__ __align__(16) float s_hrec[3][68];   // recurrent h per layer
    __shared__ __align__(16) float s_z[3][2][256];  // [layer][side][col] rows0-63 dots, cols 0..255
    __shared__ float s_parte[3][2][4];              // [layer][side][col-256] FULL dots, cols 256..259

    const int bat = blockIdx.x;
    const int tid = threadIdx.x;
    const float* xb   = x   + (size_t)bat * TT * HH;
    float*       outb = out + (size_t)bat * TT * HH;

    for (int i = tid; i < 3 * 68; i += BLOCK) { (&s_hin[0][0])[i] = 0.0f; (&s_hrec[0][0])[i] = 0.0f; }

    const bool isG  = (tid < NGATE);
    const int  atid = tid - NGATE;        // aux id 0..255
    const int  awv  = (atid >> 6) & 3;    // aux wave 0..3 (block waves 8..11 -> SIMD 0..3)
    const int  al   = atid & 63;          // aux lane

    // ---------------- gate role (tid < 512): rows 0..63 only ----------------
    const int w    = tid & 3;             // k-window: rows 16w..16w+15
    const int side = tid >> 8;            // 0 = W (reads hin), 1 = U (reads hrec)
    const int col0 = ((tid >> 2) & 63) * 4;
    const float* M = side ? U : W;

    float4 wa0, wa1, wa2, wa3, wb0, wb1, wb2, wb3,
           wc0, wc1, wc2, wc3, wd0, wd1, wd2, wd3;
#define WLD(v, c, q)                                                          \
    do {                                                                      \
        v.x = isG ? M[(16 * w + 4 * (q) + 0) * G4 + col0 + (c)] : 0.0f;       \
        v.y = isG ? M[(16 * w + 4 * (q) + 1) * G4 + col0 + (c)] : 0.0f;       \
        v.z = isG ? M[(16 * w + 4 * (q) + 2) * G4 + col0 + (c)] : 0.0f;       \
        v.w = isG ? M[(16 * w + 4 * (q) + 3) * G4 + col0 + (c)] : 0.0f;       \
        KEEP4(v);                                                             \
    } while (0)
    WLD(wa0, 0, 0); WLD(wa1, 0, 1); WLD(wa2, 0, 2); WLD(wa3, 0, 3);
    WLD(wb0, 1, 0); WLD(wb1, 1, 1); WLD(wb2, 1, 2); WLD(wb3, 1, 3);
    WLD(wc0, 2, 0); WLD(wc1, 2, 1); WLD(wc2, 2, 2); WLD(wc3, 2, 3);
    WLD(wd0, 3, 0); WLD(wd1, 3, 1); WLD(wd2, 3, 2); WLD(wd3, 3, 3);
#undef WLD

    // ---------------- aux roles (tid >= 512) ----------------
    // extras: lanes 0..7 of each aux wave; col 256+awv; FULL 65-row dot (incl row 64)
    const bool isE = (!isG) && (al < 8);
    const int  es  = (al >> 2) & 1;
    const int  ew  = al & 3;
    const int  colE = 256 + awv;
    const float* ME = es ? U : W;
    float4 e0, e1, e2, e3;
#define ELD(v, q)                                                             \
    do {                                                                      \
        v.x = isE ? ME[(16 * ew + 4 * (q) + 0) * G4 + colE] : 0.0f;           \
        v.y = isE ? ME[(16 * ew + 4 * (q) + 1) * G4 + colE] : 0.0f;           \
        v.z = isE ? ME[(16 * ew + 4 * (q) + 2) * G4 + colE] : 0.0f;           \
        v.w = isE ? ME[(16 * ew + 4 * (q) + 3) * G4 + colE] : 0.0f;           \
        KEEP4(v);                                                             \
    } while (0)
    ELD(e0, 0); ELD(e1, 1); ELD(e2, 2); ELD(e3, 3);
#undef ELD
    float esc = (isE && ew == 3) ? ME[64 * G4 + colE] : 0.0f; KEEP(esc);

    // Phase B: waves 8..10 -> layer awv, cell al; wave 11 lanes 0..2 -> layer al, cell 64
    const bool isB   = (!isG) && (awv < 3);
    const bool isB64 = (!isG) && (awv == 3) && (al < 3);
    const int  cl = isB ? awv : (isB64 ? al : 0);
    const int  cn = isB ? al : 64;
    const bool anyB = isB || isB64;
    const float bz0 = anyB ? bv[cn]       : 0.0f;
    const float bz1 = anyB ? bv[65 + cn]  : 0.0f;
    const float bz2 = anyB ? bv[130 + cn] : 0.0f;
    const float bz3 = anyB ? bv[195 + cn] : 0.0f;
    // row-64 tail weights for this cell's 4 gate columns (both sides)
    const float tW0 = anyB ? W[64 * G4 + cn]        : 0.0f;
    const float tW1 = anyB ? W[64 * G4 + 65 + cn]   : 0.0f;
    const float tW2 = anyB ? W[64 * G4 + 130 + cn]  : 0.0f;
    const float tW3 = anyB ? W[64 * G4 + 195 + cn]  : 0.0f;
    const float tU0 = anyB ? U[64 * G4 + cn]        : 0.0f;
    const float tU1 = anyB ? U[64 * G4 + 65 + cn]   : 0.0f;
    const float tU2 = anyB ? U[64 * G4 + 130 + cn]  : 0.0f;
    const float tU3 = anyB ? U[64 * G4 + 195 + cn]  : 0.0f;
    float creg = 0.0f;

    // prefetch: wave 11 lanes 0..63 -> pidx = al; lane 63 also handles pidx 64
    const bool isP  = (!isG) && (awv == 3);
    const bool isP2 = isP && (al == 63);
    const int  pidx = al;
    float cur0 = 0.0f, nxt0 = 0.0f, cur1 = 0.0f, nxt1 = 0.0f;

    __syncthreads();   // race fix: zero-init completes before x(0) lands in s_hin[0]

    if (isP) {
        s_hin[0][pidx] = xb[pidx];
        cur0 = xb[HH + pidx];
        if (isP2) { s_hin[0][64] = xb[64]; cur1 = xb[HH + 64]; }
    }
    __syncthreads();

    for (int r = 0; r < TT + 2; ++r) {
        // ---------------- Phase A ----------------
        if (isP) {  // issue x(r+2) early
            const int tn = r + 2;
            nxt0 = (tn < TT) ? xb[(size_t)tn * HH + pidx] : 0.0f;
            if (isP2) nxt1 = (tn < TT) ? xb[(size_t)tn * HH + 64] : 0.0f;
        }
        // aux-B: preload h64 values for the tail (stable during Phase A;
        // reading them here avoids racing the cell-64 writes in Phase B)
        float hin64r = 0.0f, hrec64r = 0.0f;
        if (anyB && (unsigned)(r - cl) < TT) {
            hin64r  = s_hin[cl][64];
            hrec64r = s_hrec[cl][64];
        }
        if (isG) {
#pragma unroll
            for (int l = 0; l < 3; ++l) {
                if ((unsigned)(r - l) < TT) {
                    const float* hb = side ? &s_hrec[l][0] : &s_hin[l][0];
                    const float4* h4 = (const float4*)(hb + 16 * w);
                    float a0 = 0.0f, b0 = 0.0f, a1 = 0.0f, b1 = 0.0f,
                          a2 = 0.0f, b2 = 0.0f, a3 = 0.0f, b3 = 0.0f;
#define GBLK(q, HV)                                                           \
    { a0 = fmaf(HV.x, wa##q.x, a0); b0 = fmaf(HV.y, wa##q.y, b0);             \
      a0 = fmaf(HV.z, wa##q.z, a0); b0 = fmaf(HV.w, wa##q.w, b0);             \
      a1 = fmaf(HV.x, wb##q.x, a1); b1 = fmaf(HV.y, wb##q.y, b1);             \
      a1 = fmaf(HV.z, wb##q.z, a1); b1 = fmaf(HV.w, wb##q.w, b1);             \
      a2 = fmaf(HV.x, wc##q.x, a2); b2 = fmaf(HV.y, wc##q.y, b2);             \
      a2 = fmaf(HV.z, wc##q.z, a2); b2 = fmaf(HV.w, wc##q.w, b2);             \
      a3 = fmaf(HV.x, wd##q.x, a3); b3 = fmaf(HV.y, wd##q.y, b3);             \
      a3 = fmaf(HV.z, wd##q.z, a3); b3 = fmaf(HV.w, wd##q.w, b3); }
                    { float4 Hq = h4[0]; GBLK(0, Hq); }
                    { float4 Hq = h4[1]; GBLK(1, Hq); }
                    { float4 Hq = h4[2]; GBLK(2, Hq); }
                    { float4 Hq = h4[3]; GBLK(3, Hq); }
#undef GBLK
                    float z0 = qsum(a0 + b0);
                    float z1 = qsum(a1 + b1);
                    float z2 = qsum(a2 + b2);
                    float z3 = qsum(a3 + b3);
                    if (w == 0)
                        *(float4*)&s_z[l][side][col0] = make_float4(z0, z1, z2, z3);
                }
            }
        } else if (isE) {
#pragma unroll
            for (int l = 0; l < 3; ++l) {
                if ((unsigned)(r - l) < TT) {
                    const float* hb = es ? &s_hrec[l][0] : &s_hin[l][0];
                    const float4* h4 = (const float4*)(hb + 16 * ew);
                    const float4 H0 = h4[0], H1 = h4[1], H2 = h4[2], H3 = h4[3];
                    const float  h64 = hb[64];
                    float u0, u1;
                    u0 = H0.x * e0.x;           u1 = H0.y * e0.y;
                    u0 = fmaf(H0.z, e0.z, u0);  u1 = fmaf(H0.w, e0.w, u1);
                    u0 = fmaf(H1.x, e1.x, u0);  u1 = fmaf(H1.y, e1.y, u1);
                    u0 = fmaf(H1.z, e1.z, u0);  u1 = fmaf(H1.w, e1.w, u1);
                    u0 = fmaf(H2.x, e2.x, u0);  u1 = fmaf(H2.y, e2.y, u1);
                    u0 = fmaf(H2.z, e2.z, u0);  u1 = fmaf(H2.w, e2.w, u1);
                    u0 = fmaf(H3.x, e3.x, u0);  u1 = fmaf(H3.y, e3.y, u1);
                    u0 = fmaf(H3.z, e3.z, u0);  u1 = fmaf(H3.w, e3.w, u1);
                    u0 = fmaf(h64, esc, u0);
                    float ea = qsum(u0 + u1);
                    if (ew == 0) s_parte[l][es][awv] = ea;
                }
            }
        }
        __syncthreads();

        // ---------------- Phase B (aux waves) ----------------
        if (anyB) {
            if ((unsigned)(r - cl) < TT) {
                float zi = bz0 + s_z[cl][0][cn]       + s_z[cl][1][cn];
                float zf = bz1 + s_z[cl][0][65 + cn]  + s_z[cl][1][65 + cn];
                float zg = bz2 + s_z[cl][0][130 + cn] + s_z[cl][1][130 + cn];
                zi = fmaf(hin64r, tW0, fmaf(hrec64r, tU0, zi));
                zf = fmaf(hin64r, tW1, fmaf(hrec64r, tU1, zf));
                zg = fmaf(hin64r, tW2, fmaf(hrec64r, tU2, zg));
                float zo;
                if (cn < 61) {
                    zo = bz3 + s_z[cl][0][195 + cn] + s_z[cl][1][195 + cn];
                    zo = fmaf(hin64r, tW3, fmaf(hrec64r, tU3, zo));
                } else {
                    zo = bz3 + s_parte[cl][0][cn - 61] + s_parte[cl][1][cn - 61];
                }
                const float ig = sigm(zi), fg = sigm(zf), gg = tanha(zg), og = sigm(zo);
                creg = fmaf(fg, creg, ig * gg);
                const float h = og * tanha(creg);
                s_hrec[cl][cn] = h;
                if (cl < 2) s_hin[cl + 1][cn] = h;
                else        outb[(size_t)(r - cl) * HH + cn] = h;   // stream h2 to out
            }
        }
        if (isP) {
            if (r + 1 < TT) {
                s_hin[0][pidx] = cur0;
                if (isP2) s_hin[0][64] = cur1;
            }
            cur0 = nxt0; cur1 = nxt1;
        }
        __syncthreads();
    }
}

// ---- kernel 2: in-place dense head over d_out: y = h2 @ Wd + bd ----
__global__ void __launch_bounds__(256, 1)
dense_head(float* __restrict__ io, const float* __restrict__ Wd, const float* __restrict__ bd)
{
    __shared__ __align__(16) float s_h[DROWS][68];
    __shared__ float s_wd[HH][HH];
    __shared__ float s_bd[HH];

    const int tid = threadIdx.x;
    float* base = io + (size_t)blockIdx.x * DROWS * HH;

    for (int i = tid; i < DROWS * HH; i += 256) {
        const int row = i / HH, k = i - row * HH;
        s_h[row][k] = base[i];
    }
    for (int i = tid; i < HH * HH; i += 256) (&s_wd[0][0])[i] = Wd[i];
    if (tid < HH) s_bd[tid] = bd[tid];
    __syncthreads();

    for (int u = tid; u < DROWS * HH; u += 256) {
        const int row = u / HH, c = u - row * HH;
        const float4* hp = (const float4*)&s_h[row][0];
        float acc = s_bd[c];
#pragma unroll
        for (int k4 = 0; k4 < 16; ++k4) {
            const float4 hv = hp[k4];
            acc = fmaf(hv.x, s_wd[4 * k4 + 0][c], acc);
            acc = fmaf(hv.y, s_wd[4 * k4 + 1][c], acc);
            acc = fmaf(hv.z, s_wd[4 * k4 + 2][c], acc);
            acc = fmaf(hv.w, s_wd[4 * k4 + 3][c], acc);
        }
        acc = fmaf(s_h[row][64], s_wd[64][c], acc);
        base[u] = acc;   // safe: all reads come from LDS copies
    }
}

extern "C" void kernel_launch(void* const* d_in, const int* in_sizes, int n_in,
                              void* d_out, int out_size, void* d_ws, size_t ws_size,
                              hipStream_t stream)
{
    const float* x  = (const float*)d_in[0];
    const float* W  = (const float*)d_in[1];
    const float* U  = (const float*)d_in[2];
    const float* bv = (const float*)d_in[3];
    const float* Wd = (const float*)d_in[4];
    const float* bd = (const float*)d_in[5];
    float* out = (float*)d_out;

    hipLaunchKernelGGL(charrnn_rec, dim3(NB), dim3(BLOCK), 0, stream, x, W, U, bv, out);
    hipLaunchKernelGGL(dense_head, dim3(NB * TT / DROWS), dim3(256), 0, stream, out, Wd, bd);
}